// Round 26
// baseline (87.399 us; speedup 1.0000x reference)
//
#include <hip/hip_runtime.h>
#include <stdint.h>

// CorrelationLayer via MFMA Gram tiles — R21 champion + kb-innermost staging
// decode (bank-uniform ds_writes).
// out[j*7+i, h, w] = sum_c x[c,h,w] * y[c,h+j-3,w+i-3], zero-padded.
//
// R26 = R21 byte-exact (54.9us: 512 thr / 8 waves = 4 output rows x 32-px
// slab, NROW=10, LDS double-buffer 2x32KB, 2 blocks/CU at the 128-reg tier,
// issue-early/write-late for unit A + af, has2 staged plainly) with ONE
// change: staging unit decode is kb-INNERMOST (kb=u&3, c2=(u>>2)%20,
// row=u/80; same bijection over 800 units, same ldso formula). Old
// c2-innermost gave 20 same-kb lanes at 160B stride -> start banks
// {x3,x3,x3,x3,x2,x2,x2,x2} over 8 quads = ~3-way write imbalance (5.07M
// conflict cycles ~ 8% of runtime). New: each lane-quad covers one
// contiguous 64B k-region (kbs = XOR permutation of kb), quad starts cycle
// {0,8,16,24} -> every bank hit exactly 8x per wave b128 write = minimum.
// R25 lesson: setprio null (dropped). R22-R24 lesson: write region tolerates
// no reordering (spills) — decode remap has zero register cost.
// All math byte-identical to R21: col-pair staging (8x float2 -> pkbf ->
// 2x b128, kb-XOR swizzle kb^((c2>>2)&3), read-inverted g^((col>>3)&3));
// A/B frag lane {m|n}=l&15, k=(l>>4)*8+e; C/D col=lane&15,row=(lane>>4)*4+reg;
// af per-chunk held as floats; extraction slab 16x34 f32, i=g / g+4 (g<3).
// Grid 96 hg x 16 slabs = 1536; XCD k owns hg [12k,12k+12), slab-fastest.

typedef __attribute__((ext_vector_type(8))) short short8;
typedef __attribute__((ext_vector_type(4))) float floatx4;

constexpr int C = 128;
constexpr int H = 384;
constexpr int W = 512;
constexpr int HW = H * W;

constexpr int NROW = 10;              // rows h0-3 .. h0+6
constexpr int NCOL = 40;              // LDS col 0 = abs ws_blk - 4
constexpr int KP   = 40;              // bf16 per col (32 k + 8 pad) = 80 B
constexpr int ROWB = NCOL * KP * 2;   // 3200 B per row
constexpr int BUFE = NROW * NCOL * KP;        // 16000 bf16 elems (32 KB)
constexpr int NUNIT = NROW * 4 * (NCOL / 2);  // 800 staging units

__device__ __forceinline__ uint32_t pkbf(float a, float b) {
  uint32_t ua = (__float_as_uint(a) + 0x8000u) >> 16;
  uint32_t ub = (__float_as_uint(b) + 0x8000u) & 0xffff0000u;
  return ua | ub;
}

union S8U { uint32_t u[4]; short8 s; };

// decode staging unit u -> source pointer, validity, LDS element offset.
// kb-INNERMOST: consecutive lanes cover kb=0..3 of one (row, col-pair) ->
// each lane-quad writes one contiguous 64B k-region -> bank-uniform.
__device__ __forceinline__ void unit_decode(const float* __restrict__ y,
                                            int kc, int h0, int ws_blk, int u,
                                            const float*& src, bool& val,
                                            int& ldso) {
  const int kb  = u & 3;
  const int c2  = (u >> 2) % 20;
  const int row = u / 80;                    // 0..9
  const int r_abs = h0 - 3 + row;
  const int cb    = ws_blk - 4 + 2 * c2;     // even -> no pair straddle
  val = (r_abs >= 0) & (r_abs < H) & (cb >= 0) & (cb <= W - 2);
  const int r  = r_abs < 0 ? 0 : (r_abs >= H ? H - 1 : r_abs);
  const int cc = cb < 0 ? 0 : (cb > W - 2 ? W - 2 : cb);
  src = y + (size_t)(kc * 32 + kb * 8) * HW + (size_t)r * W + cc;
  const int kbs = kb ^ ((c2 >> 2) & 3);      // bank swizzle (16B granule)
  ldso = (row * NCOL + 2 * c2) * KP + kbs * 8;
}

__device__ __forceinline__ void unit_store(uint16_t* __restrict__ buf,
                                           const float2 f[8], bool val,
                                           int ldso) {
  uint4 v0, v1;
  v0.x = pkbf(f[0].x, f[1].x); v0.y = pkbf(f[2].x, f[3].x);
  v0.z = pkbf(f[4].x, f[5].x); v0.w = pkbf(f[6].x, f[7].x);
  v1.x = pkbf(f[0].y, f[1].y); v1.y = pkbf(f[2].y, f[3].y);
  v1.z = pkbf(f[4].y, f[5].y); v1.w = pkbf(f[6].y, f[7].y);
  if (!val) { v0 = make_uint4(0, 0, 0, 0); v1 = make_uint4(0, 0, 0, 0); }
  *reinterpret_cast<uint4*>(&buf[ldso])      = v0;
  *reinterpret_cast<uint4*>(&buf[ldso + KP]) = v1;   // same quad -> same swz
}

__device__ __forceinline__ void stage_plain(const float* __restrict__ y,
                                            uint16_t* __restrict__ buf,
                                            int kc, int h0, int ws_blk, int u) {
  const float* src; bool val; int ldso;
  unit_decode(y, kc, h0, ws_blk, u, src, val, ldso);
  float2 f[8];
#pragma unroll
  for (int e = 0; e < 8; ++e)
    f[e] = *reinterpret_cast<const float2*>(src + (size_t)e * HW);
  unit_store(buf, f, val, ldso);
}

__global__ __launch_bounds__(512, 4)
void corr_mfma(const float* __restrict__ x, const float* __restrict__ y,
               float* __restrict__ out) {
  __shared__ uint16_t ys[2][BUFE];           // 64000 B

  const int bid  = blockIdx.x;
  const int xcd  = bid & 7;
  const int idx  = bid >> 3;                 // 0..191
  const int hg   = xcd * 12 + (idx >> 4);    // 0..95
  const int slab = idx & 15;
  const int h0     = hg * 4;
  const int ws_blk = slab * 32;
  const int tid  = threadIdx.x;
  const int wv   = tid >> 6;                 // 0..7
  const int lane = tid & 63;
  const int m  = lane & 15;
  const int g  = lane >> 4;
  const int dh = wv >> 1;                    // 0..3
  const int ww = wv & 1;                     // 0..1
  const int h  = h0 + dh;
  const int ws = ws_blk + ww * 16;

  const bool has2 = (tid < NUNIT - 512);     // 288 threads own a 2nd unit

  floatx4 acc[7][2];
#pragma unroll
  for (int j = 0; j < 7; ++j) {
    acc[j][0] = (floatx4){0.f, 0.f, 0.f, 0.f};
    acc[j][1] = (floatx4){0.f, 0.f, 0.f, 0.f};
  }

  // per-lane b128 read byte-offsets within a row slab (swizzle-inverted)
  const int col0 = ww * 16 + m + 1;          // abs ws-3+m
  int col1 = col0 + 16;                      // tile1; clamp unused lanes
  if (col1 > NCOL - 1) col1 = NCOL - 1;
  const int fb0 = col0 * (KP * 2) + (g ^ ((col0 >> 3) & 3)) * 16;
  const int fb1 = col1 * (KP * 2) + (g ^ ((col1 >> 3) & 3)) * 16;

  const float* xb = x + (size_t)(g * 8) * HW + (size_t)h * W + (ws + m);

  // ---- prologue: stage chunk 0 into ys[0]; af for chunk 0 ----
  stage_plain(y, ys[0], 0, h0, ws_blk, tid);
  if (has2) stage_plain(y, ys[0], 0, h0, ws_blk, 512 + tid);
  short8 af_cur;
  {
    float f[8];
#pragma unroll
    for (int e = 0; e < 8; ++e) f[e] = xb[(size_t)e * HW];
    S8U s;
    s.u[0] = pkbf(f[0], f[1]);
    s.u[1] = pkbf(f[2], f[3]);
    s.u[2] = pkbf(f[4], f[5]);
    s.u[3] = pkbf(f[6], f[7]);
    af_cur = s.s;
  }
  __syncthreads();

  // ---- main loop: issue(kc+1) -> compute(kc) -> write(kc+1) -> barrier ----
#pragma unroll
  for (int kc = 0; kc < 4; ++kc) {
    // (1) issue next chunk's unit-A loads + next af floats (held in regs)
    float2 F[8];
    float axf[8];
    bool v = false; int o = 0;
    if (kc < 3) {
      const float* s1;
      unit_decode(y, kc + 1, h0, ws_blk, tid, s1, v, o);
#pragma unroll
      for (int e = 0; e < 8; ++e)
        F[e] = *reinterpret_cast<const float2*>(s1 + (size_t)e * HW);
#pragma unroll
      for (int e = 0; e < 8; ++e)
        axf[e] = xb[(size_t)((kc + 1) * 32 + e) * HW];
    }

    // (2) compute chunk kc from ys[kc&1]: B row = dh + j
    const uint16_t* buf = ys[kc & 1];
#pragma unroll
    for (int j = 0; j < 7; ++j) {
      const uint8_t* rb =
          reinterpret_cast<const uint8_t*>(buf) + (dh + j) * ROWB;
      const short8 b0 = *reinterpret_cast<const short8*>(rb + fb0);
      const short8 b1 = *reinterpret_cast<const short8*>(rb + fb1);
      acc[j][0] = __builtin_amdgcn_mfma_f32_16x16x32_bf16(af_cur, b0, acc[j][0], 0, 0, 0);
      acc[j][1] = __builtin_amdgcn_mfma_f32_16x16x32_bf16(af_cur, b1, acc[j][1], 0, 0, 0);
    }

    // (3) write next chunk into ys[(kc+1)&1]; has2 unit staged plainly
    if (kc < 3) {
      uint16_t* nbuf = ys[(kc + 1) & 1];
      unit_store(nbuf, F, v, o);
      if (has2) stage_plain(y, nbuf, kc + 1, h0, ws_blk, 512 + tid);
      S8U s;
      s.u[0] = pkbf(axf[0], axf[1]);
      s.u[1] = pkbf(axf[2], axf[3]);
      s.u[2] = pkbf(axf[4], axf[5]);
      s.u[3] = pkbf(axf[6], axf[7]);
      af_cur = s.s;
    }
    __syncthreads();
  }

  // ---- extraction: per-wave 16x34 f32 slab (reuses ys[0]; 8*2176B fits) ----
  float* slabp = reinterpret_cast<float*>(&ys[0][0]) + wv * 544;
#pragma unroll
  for (int j = 0; j < 7; ++j) {
#pragma unroll
    for (int q = 0; q < 4; ++q) {
      slabp[(g * 4 + q) * 34 + m]      = acc[j][0][q];   // cols 0..15
      slabp[(g * 4 + q) * 34 + 16 + m] = acc[j][1][q];   // cols 16..31
    }
    const float vo0 = slabp[m * 34 + m + g];             // i = g
    const float vo1 = slabp[m * 34 + m + g + 4];         // i = g+4 (g<3)
    float* ob = out + (size_t)(j * 7 + g) * HW + (size_t)h * W + (ws + m);
    *ob = vo0;
    if (g < 3) ob[(size_t)4 * HW] = vo1;
  }
}

extern "C" void kernel_launch(void* const* d_in, const int* in_sizes, int n_in,
                              void* d_out, int out_size, void* d_ws, size_t ws_size,
                              hipStream_t stream) {
  const float* x = (const float*)d_in[0];
  const float* y = (const float*)d_in[1];
  float* out = (float*)d_out;
  corr_mfma<<<dim3(96 * 16), dim3(512), 0, stream>>>(x, y, out);
}

// Round 27
// 55.100 us; speedup vs baseline: 1.5862x; 1.5862x over previous
//
#include <hip/hip_runtime.h>
#include <stdint.h>

// CorrelationLayer via MFMA Gram tiles — CHAMPION (R21, 54.9us), restored.
// out[j*7+i, h, w] = sum_c x[c,h,w] * y[c,h+j-3,w+i-3], zero-padded.
//
// Final structure: block = 512 thr / 8 waves = 4 output rows x 32-px slab;
// wave (dh 0..3, ww 0..1) owns (h0+dh, 16-px tile), all 7 j (acc[7][2]).
// LDS: double-buffered y tile [10 rows][40 cols][k32 pad40] bf16 (2x32KB),
// k-contiguous per col (80B); kb-XOR bank swizzle kb^((c2>>2)&3) on write,
// read-inverted g^((col>>3)&3). 2 blocks/CU at the 128-reg tier (VGPR 64
// arch + 56 AGPR acc): cross-block phase overlap is the latency cover.
// Per chunk: issue(kc+1 unit-A loads + af floats) -> compute(kc) 14 MFMA ->
// write(kc+1) + plain-stage has2 unit -> ONE barrier.
// Session-closed doors: >=24 held regs in write region spills (R22/R23/R24);
// setprio null (R25); kb-innermost decode breaks global coalescing (R26);
// j-split occupancy loses to staging redundancy (R19); mega-stage/barrier
// count neutral (R17); 3rd block/CU unreachable at acc+af footprint (R16).
// Verified math: staging decode/clamp/mask; A/B frag lane {m|n}=l&15,
// k=(l>>4)*8+e; C/D col=lane&15, row=(lane>>4)*4+reg; extraction slab
// 16x34 f32, i=g / g+4 (g<3). absmax 0.25 << 1.22 threshold (bf16 inputs,
// fp32 accum). Grid 96 hg x 16 slabs = 1536; XCD k owns hg [12k,12k+12).

typedef __attribute__((ext_vector_type(8))) short short8;
typedef __attribute__((ext_vector_type(4))) float floatx4;

constexpr int C = 128;
constexpr int H = 384;
constexpr int W = 512;
constexpr int HW = H * W;

constexpr int NROW = 10;              // rows h0-3 .. h0+6
constexpr int NCOL = 40;              // LDS col 0 = abs ws_blk - 4
constexpr int KP   = 40;              // bf16 per col (32 k + 8 pad) = 80 B
constexpr int ROWB = NCOL * KP * 2;   // 3200 B per row
constexpr int BUFE = NROW * NCOL * KP;        // 16000 bf16 elems (32 KB)
constexpr int NUNIT = NROW * 4 * (NCOL / 2);  // 800 staging units

__device__ __forceinline__ uint32_t pkbf(float a, float b) {
  uint32_t ua = (__float_as_uint(a) + 0x8000u) >> 16;
  uint32_t ub = (__float_as_uint(b) + 0x8000u) & 0xffff0000u;
  return ua | ub;
}

union S8U { uint32_t u[4]; short8 s; };

// decode staging unit u -> source pointer, validity, LDS element offset
// (c2-innermost: consecutive lanes read consecutive col-pairs -> coalesced)
__device__ __forceinline__ void unit_decode(const float* __restrict__ y,
                                            int kc, int h0, int ws_blk, int u,
                                            const float*& src, bool& val,
                                            int& ldso) {
  const int c2  = u % 20;
  const int kb  = (u / 20) & 3;
  const int row = u / 80;                    // 0..9
  const int r_abs = h0 - 3 + row;
  const int cb    = ws_blk - 4 + 2 * c2;     // even -> no pair straddle
  val = (r_abs >= 0) & (r_abs < H) & (cb >= 0) & (cb <= W - 2);
  const int r  = r_abs < 0 ? 0 : (r_abs >= H ? H - 1 : r_abs);
  const int cc = cb < 0 ? 0 : (cb > W - 2 ? W - 2 : cb);
  src = y + (size_t)(kc * 32 + kb * 8) * HW + (size_t)r * W + cc;
  const int kbs = kb ^ ((c2 >> 2) & 3);      // bank swizzle (16B granule)
  ldso = (row * NCOL + 2 * c2) * KP + kbs * 8;
}

__device__ __forceinline__ void unit_store(uint16_t* __restrict__ buf,
                                           const float2 f[8], bool val,
                                           int ldso) {
  uint4 v0, v1;
  v0.x = pkbf(f[0].x, f[1].x); v0.y = pkbf(f[2].x, f[3].x);
  v0.z = pkbf(f[4].x, f[5].x); v0.w = pkbf(f[6].x, f[7].x);
  v1.x = pkbf(f[0].y, f[1].y); v1.y = pkbf(f[2].y, f[3].y);
  v1.z = pkbf(f[4].y, f[5].y); v1.w = pkbf(f[6].y, f[7].y);
  if (!val) { v0 = make_uint4(0, 0, 0, 0); v1 = make_uint4(0, 0, 0, 0); }
  *reinterpret_cast<uint4*>(&buf[ldso])      = v0;
  *reinterpret_cast<uint4*>(&buf[ldso + KP]) = v1;   // same quad -> same swz
}

__device__ __forceinline__ void stage_plain(const float* __restrict__ y,
                                            uint16_t* __restrict__ buf,
                                            int kc, int h0, int ws_blk, int u) {
  const float* src; bool val; int ldso;
  unit_decode(y, kc, h0, ws_blk, u, src, val, ldso);
  float2 f[8];
#pragma unroll
  for (int e = 0; e < 8; ++e)
    f[e] = *reinterpret_cast<const float2*>(src + (size_t)e * HW);
  unit_store(buf, f, val, ldso);
}

__global__ __launch_bounds__(512, 4)
void corr_mfma(const float* __restrict__ x, const float* __restrict__ y,
               float* __restrict__ out) {
  __shared__ uint16_t ys[2][BUFE];           // 64000 B

  const int bid  = blockIdx.x;
  const int xcd  = bid & 7;
  const int idx  = bid >> 3;                 // 0..191
  const int hg   = xcd * 12 + (idx >> 4);    // 0..95
  const int slab = idx & 15;
  const int h0     = hg * 4;
  const int ws_blk = slab * 32;
  const int tid  = threadIdx.x;
  const int wv   = tid >> 6;                 // 0..7
  const int lane = tid & 63;
  const int m  = lane & 15;
  const int g  = lane >> 4;
  const int dh = wv >> 1;                    // 0..3
  const int ww = wv & 1;                     // 0..1
  const int h  = h0 + dh;
  const int ws = ws_blk + ww * 16;

  const bool has2 = (tid < NUNIT - 512);     // 288 threads own a 2nd unit

  floatx4 acc[7][2];
#pragma unroll
  for (int j = 0; j < 7; ++j) {
    acc[j][0] = (floatx4){0.f, 0.f, 0.f, 0.f};
    acc[j][1] = (floatx4){0.f, 0.f, 0.f, 0.f};
  }

  // per-lane b128 read byte-offsets within a row slab (swizzle-inverted)
  const int col0 = ww * 16 + m + 1;          // abs ws-3+m
  int col1 = col0 + 16;                      // tile1; clamp unused lanes
  if (col1 > NCOL - 1) col1 = NCOL - 1;
  const int fb0 = col0 * (KP * 2) + (g ^ ((col0 >> 3) & 3)) * 16;
  const int fb1 = col1 * (KP * 2) + (g ^ ((col1 >> 3) & 3)) * 16;

  const float* xb = x + (size_t)(g * 8) * HW + (size_t)h * W + (ws + m);

  // ---- prologue: stage chunk 0 into ys[0]; af for chunk 0 ----
  stage_plain(y, ys[0], 0, h0, ws_blk, tid);
  if (has2) stage_plain(y, ys[0], 0, h0, ws_blk, 512 + tid);
  short8 af_cur;
  {
    float f[8];
#pragma unroll
    for (int e = 0; e < 8; ++e) f[e] = xb[(size_t)e * HW];
    S8U s;
    s.u[0] = pkbf(f[0], f[1]);
    s.u[1] = pkbf(f[2], f[3]);
    s.u[2] = pkbf(f[4], f[5]);
    s.u[3] = pkbf(f[6], f[7]);
    af_cur = s.s;
  }
  __syncthreads();

  // ---- main loop: issue(kc+1) -> compute(kc) -> write(kc+1) -> barrier ----
#pragma unroll
  for (int kc = 0; kc < 4; ++kc) {
    // (1) issue next chunk's unit-A loads + next af floats (held in regs)
    float2 F[8];
    float axf[8];
    bool v = false; int o = 0;
    if (kc < 3) {
      const float* s1;
      unit_decode(y, kc + 1, h0, ws_blk, tid, s1, v, o);
#pragma unroll
      for (int e = 0; e < 8; ++e)
        F[e] = *reinterpret_cast<const float2*>(s1 + (size_t)e * HW);
#pragma unroll
      for (int e = 0; e < 8; ++e)
        axf[e] = xb[(size_t)((kc + 1) * 32 + e) * HW];
    }

    // (2) compute chunk kc from ys[kc&1]: B row = dh + j
    const uint16_t* buf = ys[kc & 1];
#pragma unroll
    for (int j = 0; j < 7; ++j) {
      const uint8_t* rb =
          reinterpret_cast<const uint8_t*>(buf) + (dh + j) * ROWB;
      const short8 b0 = *reinterpret_cast<const short8*>(rb + fb0);
      const short8 b1 = *reinterpret_cast<const short8*>(rb + fb1);
      acc[j][0] = __builtin_amdgcn_mfma_f32_16x16x32_bf16(af_cur, b0, acc[j][0], 0, 0, 0);
      acc[j][1] = __builtin_amdgcn_mfma_f32_16x16x32_bf16(af_cur, b1, acc[j][1], 0, 0, 0);
    }

    // (3) write next chunk into ys[(kc+1)&1]; has2 unit staged plainly
    if (kc < 3) {
      uint16_t* nbuf = ys[(kc + 1) & 1];
      unit_store(nbuf, F, v, o);
      if (has2) stage_plain(y, nbuf, kc + 1, h0, ws_blk, 512 + tid);
      S8U s;
      s.u[0] = pkbf(axf[0], axf[1]);
      s.u[1] = pkbf(axf[2], axf[3]);
      s.u[2] = pkbf(axf[4], axf[5]);
      s.u[3] = pkbf(axf[6], axf[7]);
      af_cur = s.s;
    }
    __syncthreads();
  }

  // ---- extraction: per-wave 16x34 f32 slab (reuses ys[0]; 8*2176B fits) ----
  float* slabp = reinterpret_cast<float*>(&ys[0][0]) + wv * 544;
#pragma unroll
  for (int j = 0; j < 7; ++j) {
#pragma unroll
    for (int q = 0; q < 4; ++q) {
      slabp[(g * 4 + q) * 34 + m]      = acc[j][0][q];   // cols 0..15
      slabp[(g * 4 + q) * 34 + 16 + m] = acc[j][1][q];   // cols 16..31
    }
    const float vo0 = slabp[m * 34 + m + g];             // i = g
    const float vo1 = slabp[m * 34 + m + g + 4];         // i = g+4 (g<3)
    float* ob = out + (size_t)(j * 7 + g) * HW + (size_t)h * W + (ws + m);
    *ob = vo0;
    if (g < 3) ob[(size_t)4 * HW] = vo1;
  }
}

extern "C" void kernel_launch(void* const* d_in, const int* in_sizes, int n_in,
                              void* d_out, int out_size, void* d_ws, size_t ws_size,
                              hipStream_t stream) {
  const float* x = (const float*)d_in[0];
  const float* y = (const float*)d_in[1];
  float* out = (float*)d_out;
  corr_mfma<<<dim3(96 * 16), dim3(512), 0, stream>>>(x, y, out);
}